// Round 1
// baseline (82.220 us; speedup 1.0000x reference)
//
#include <hip/hip_runtime.h>
#include <hip/hip_bf16.h>

// SingleDimHistLayer: soft histogram via fine-grid deposit + 145-tap convolution.
//
// Math: out[b,k] = (1/N) * sum_n [ g(u_n - k) - g(u_n - k - 1) ],  g(v)=sigmoid(2.5 v),
//       u = x*256.  Terms negligible (<4e-5, decaying e^{-2.5/step}) outside
//       |u - k - 0.5| <= 4.5  -> 9-bin window -> 145 fine taps at 1/16 resolution.
// Deposit: linear interp of each sample onto fine nodes (error O(h^2), zero-mean).
// Conv:   per-block fine hist (4097 nodes + pads) x precomputed weight vector.

constexpr int KBINS   = 256;
constexpr int FSUB    = 16;                  // fine nodes per bin
constexpr int NODES   = KBINS * FSUB + 1;    // 4097 (node at u = f/16)
constexpr int LPAD    = 64;                  // left halo (k=0 window reaches f=-64)
constexpr int TAPS    = 145;                 // window f in [16k-64, 16k+80]
constexpr int PSIZE   = LPAD + NODES + 64;   // logical padded indices [0, 4224]
// bank-skew addressing: addr = p + (p>>5); max = 4224 + 132 = 4356
constexpr int LDS_FH  = 4360;
constexpr int NPB     = 512 * 512;           // samples per batch
constexpr int BLK_PER_BATCH = 64;            // 4096 samples per block
constexpr int CHUNK   = NPB / BLK_PER_BATCH; // 4096

__device__ __forceinline__ int skew(int p) { return p + (p >> 5); }

__global__ __launch_bounds__(256)
void hist_kernel(const float* __restrict__ x, float* __restrict__ out) {
    __shared__ float fh[LDS_FH];
    __shared__ float w[TAPS];
    const int tid = threadIdx.x;

    // zero fine hist
    #pragma unroll
    for (int i = tid; i < LDS_FH; i += 256) fh[i] = 0.f;

    // precompute conv weights: w[j] = sigmoid(0.15625*(j-64)) - sigmoid(0.15625*(j-80))
    if (tid < TAPS) {
        float a = 0.15625f * (float)(tid - 64);
        float b = 0.15625f * (float)(tid - 80);
        w[tid] = 1.f / (1.f + __expf(-a)) - 1.f / (1.f + __expf(-b));
    }
    __syncthreads();

    const int b     = blockIdx.x / BLK_PER_BATCH;
    const int chunk = blockIdx.x % BLK_PER_BATCH;
    const float4* xv = (const float4*)(x + (size_t)b * NPB + (size_t)chunk * CHUNK);

    // deposit: 4096 samples/block, 4 float4 per thread
    #pragma unroll
    for (int it = 0; it < CHUNK / (4 * 256); ++it) {
        float4 v = xv[it * 256 + tid];
        float vals[4] = {v.x, v.y, v.z, v.w};
        #pragma unroll
        for (int c = 0; c < 4; ++c) {
            float s = vals[c] * (float)(KBINS * FSUB);     // position on fine grid
            s = fminf(fmaxf(s, 0.f), 4095.9995f);          // defensive clamp
            int   i0 = (int)s;
            float t  = s - (float)i0;
            int   p  = i0 + LPAD;
            atomicAdd(&fh[skew(p)],     1.f - t);
            atomicAdd(&fh[skew(p + 1)], t);
        }
    }
    __syncthreads();

    // convolve: thread k computes coarse bin k from taps [16k, 16k+144] (padded idx)
    {
        float acc = 0.f;
        const int base = tid * FSUB;
        #pragma unroll 8
        for (int j = 0; j < TAPS; ++j)
            acc += w[j] * fh[skew(base + j)];
        unsafeAtomicAdd(&out[b * KBINS + tid], acc * (1.f / (float)NPB));
    }
}

extern "C" void kernel_launch(void* const* d_in, const int* in_sizes, int n_in,
                              void* d_out, int out_size, void* d_ws, size_t ws_size,
                              hipStream_t stream) {
    const float* x = (const float*)d_in[0];
    float* out = (float*)d_out;
    const int B = in_sizes[0] / NPB;   // 8

    hipMemsetAsync(d_out, 0, (size_t)out_size * sizeof(float), stream);
    hist_kernel<<<B * BLK_PER_BATCH, 256, 0, stream>>>(x, out);
}

// Round 2
// 71.641 us; speedup vs baseline: 1.1477x; 1.1477x over previous
//
#include <hip/hip_runtime.h>
#include <hip/hip_bf16.h>

// SingleDimHistLayer: soft histogram via fine-grid deposit + 145-tap convolution.
//
// Math: out[b,k] = (1/N) * sum_n [ g(u_n - k) - g(u_n - k - 1) ],  g(v)=sigmoid(2.5 v),
//       u = x*256.  Terms negligible (<4e-5, decaying e^{-2.5/step}) outside
//       |u - k - 0.5| <= 4.5  -> 9-bin window -> 145 fine taps at 1/16 resolution.
// Deposit: NEAREST fine node (midpoint rule for uniform x: systematic error
//          -h^2/24 * w'' — 2x smaller than linear-interp trapezoid, and only
//          ONE ds_add_f32 per sample instead of two).
// Conv:   per-block fine hist (4097 nodes + pads) x precomputed weight vector.

constexpr int KBINS   = 256;
constexpr int FSUB    = 16;                  // fine nodes per bin
constexpr int NODES   = KBINS * FSUB + 1;    // 4097 (node at u = f/16)
constexpr int LPAD    = 64;                  // left halo (k=0 window reaches f=-64)
constexpr int TAPS    = 145;                 // window f in [16k-64, 16k+80]
// bank-skew addressing: addr = p + (p>>5); max logical p = 4224 -> 4356
constexpr int LDS_FH  = 4360;
constexpr int NPB     = 512 * 512;           // samples per batch
constexpr int BLK_PER_BATCH = 64;            // 4096 samples per block
constexpr int CHUNK   = NPB / BLK_PER_BATCH; // 4096

__device__ __forceinline__ int skew(int p) { return p + (p >> 5); }

__global__ __launch_bounds__(256)
void hist_kernel(const float* __restrict__ x, float* __restrict__ out) {
    __shared__ float fh[LDS_FH];
    __shared__ float w[TAPS];
    const int tid = threadIdx.x;

    // zero fine hist
    #pragma unroll
    for (int i = tid; i < LDS_FH; i += 256) fh[i] = 0.f;

    // precompute conv weights: w[j] = sigmoid(0.15625*(j-64)) - sigmoid(0.15625*(j-80))
    if (tid < TAPS) {
        float a = 0.15625f * (float)(tid - 64);
        float b = 0.15625f * (float)(tid - 80);
        w[tid] = 1.f / (1.f + __expf(-a)) - 1.f / (1.f + __expf(-b));
    }
    __syncthreads();

    const int b     = blockIdx.x / BLK_PER_BATCH;
    const int chunk = blockIdx.x % BLK_PER_BATCH;
    const float4* xv = (const float4*)(x + (size_t)b * NPB + (size_t)chunk * CHUNK);

    // deposit: 4096 samples/block, 4 float4 per thread, 1 LDS atomic per sample
    #pragma unroll
    for (int it = 0; it < CHUNK / (4 * 256); ++it) {
        float4 v = xv[it * 256 + tid];
        float vals[4] = {v.x, v.y, v.z, v.w};
        #pragma unroll
        for (int c = 0; c < 4; ++c) {
            float s = vals[c] * (float)(KBINS * FSUB);   // position on fine grid
            s = fminf(fmaxf(s, 0.f), 4096.f);            // defensive clamp
            int   p = (int)(s + 0.5f) + LPAD;            // nearest node (s >= 0)
            atomicAdd(&fh[skew(p)], 1.f);
        }
    }
    __syncthreads();

    // convolve: thread k computes coarse bin k from taps [16k, 16k+144] (padded idx)
    {
        float acc = 0.f;
        const int base = tid * FSUB;
        #pragma unroll 8
        for (int j = 0; j < TAPS; ++j)
            acc += w[j] * fh[skew(base + j)];
        unsafeAtomicAdd(&out[b * KBINS + tid], acc * (1.f / (float)NPB));
    }
}

extern "C" void kernel_launch(void* const* d_in, const int* in_sizes, int n_in,
                              void* d_out, int out_size, void* d_ws, size_t ws_size,
                              hipStream_t stream) {
    const float* x = (const float*)d_in[0];
    float* out = (float*)d_out;
    const int B = in_sizes[0] / NPB;   // 8

    hipMemsetAsync(d_out, 0, (size_t)out_size * sizeof(float), stream);
    hist_kernel<<<B * BLK_PER_BATCH, 256, 0, stream>>>(x, out);
}

// Round 3
// 71.567 us; speedup vs baseline: 1.1488x; 1.0010x over previous
//
#include <hip/hip_runtime.h>
#include <hip/hip_bf16.h>

// SingleDimHistLayer: soft histogram via fine-grid deposit + 145-tap convolution.
//
// Math: out[b,k] = (1/N) * sum_n [ g(u_n - k) - g(u_n - k - 1) ],  g(v)=sigmoid(2.5 v),
//       u = x*256.  Terms negligible outside |u - k - 0.5| <= 4.5 -> 145 fine taps
//       at 1/16 resolution.
// Deposit: nearest fine node (midpoint rule), 1 ds_add_f32 per sample.
//          Split across TWO wave-parity sub-histograms (contention probe:
//          if LDS atomics are lane-serialized this is neutral; if same-hist
//          RMW contention dominates it halves deposit time).
// Conv:   merge sub-hists, then 256 threads x 145 taps; one block per CU
//         (grid 256) so the conv runs once per 8192 samples, not per 4096.

constexpr int KBINS   = 256;
constexpr int FSUB    = 16;                  // fine nodes per bin
constexpr int LPAD    = 64;                  // left halo (k=0 window reaches f=-64)
constexpr int TAPS    = 145;                 // window f in [16k-64, 16k+80]
// bank-skew addressing: addr = p + (p>>5); max logical p = 4224 -> 4356
constexpr int LDS_FH  = 4360;                // one sub-histogram (floats)
constexpr int NPB     = 512 * 512;           // samples per batch
constexpr int BLK_PER_BATCH = 32;            // 8192 samples per block, grid = 256
constexpr int CHUNK   = NPB / BLK_PER_BATCH; // 8192

__device__ __forceinline__ int skew(int p) { return p + (p >> 5); }

__global__ __launch_bounds__(256)
void hist_kernel(const float* __restrict__ x, float* __restrict__ out) {
    __shared__ float fh[2 * LDS_FH];
    __shared__ float w[TAPS];
    const int tid = threadIdx.x;

    // zero both sub-histograms
    #pragma unroll
    for (int i = tid; i < 2 * LDS_FH; i += 256) fh[i] = 0.f;

    // conv weights: w[j] = sigmoid(0.15625*(j-64)) - sigmoid(0.15625*(j-80))
    if (tid < TAPS) {
        float a = 0.15625f * (float)(tid - 64);
        float b = 0.15625f * (float)(tid - 80);
        w[tid] = 1.f / (1.f + __expf(-a)) - 1.f / (1.f + __expf(-b));
    }
    __syncthreads();

    const int b     = blockIdx.x / BLK_PER_BATCH;
    const int chunk = blockIdx.x % BLK_PER_BATCH;
    const float4* xv = (const float4*)(x + (size_t)b * NPB + (size_t)chunk * CHUNK);

    // wave-parity sub-histogram: waves 0,2 -> fh0; waves 1,3 -> fh1
    float* myfh = fh + ((tid >> 6) & 1) * LDS_FH;

    // deposit: 8192 samples/block, 8 float4 per thread, 1 LDS atomic per sample
    #pragma unroll
    for (int it = 0; it < CHUNK / (4 * 256); ++it) {
        float4 v = xv[it * 256 + tid];
        float vals[4] = {v.x, v.y, v.z, v.w};
        #pragma unroll
        for (int c = 0; c < 4; ++c) {
            float s = vals[c] * (float)(KBINS * FSUB);   // position on fine grid
            s = fminf(fmaxf(s, 0.f), 4096.f);            // defensive clamp
            int   p = (int)(s + 0.5f) + LPAD;            // nearest node (s >= 0)
            atomicAdd(&myfh[skew(p)], 1.f);
        }
    }
    __syncthreads();

    // merge sub-hist 1 into 0
    #pragma unroll
    for (int i = tid; i < LDS_FH; i += 256) fh[i] += fh[LDS_FH + i];
    __syncthreads();

    // convolve: thread k computes coarse bin k from taps [16k, 16k+144] (padded idx)
    {
        float acc = 0.f;
        const int base = tid * FSUB;
        #pragma unroll 8
        for (int j = 0; j < TAPS; ++j)
            acc += w[j] * fh[skew(base + j)];
        unsafeAtomicAdd(&out[b * KBINS + tid], acc * (1.f / (float)NPB));
    }
}

extern "C" void kernel_launch(void* const* d_in, const int* in_sizes, int n_in,
                              void* d_out, int out_size, void* d_ws, size_t ws_size,
                              hipStream_t stream) {
    const float* x = (const float*)d_in[0];
    float* out = (float*)d_out;
    const int B = in_sizes[0] / NPB;   // 8

    hipMemsetAsync(d_out, 0, (size_t)out_size * sizeof(float), stream);
    hist_kernel<<<B * BLK_PER_BATCH, 256, 0, stream>>>(x, out);
}

// Round 4
// 62.581 us; speedup vs baseline: 1.3138x; 1.1436x over previous
//
#include <hip/hip_runtime.h>
#include <hip/hip_bf16.h>

// SingleDimHistLayer: soft histogram via fine-grid deposit + 145-tap convolution.
//
// Math: out[b,k] = (1/N) * sum_n [ g(u_n - k) - g(u_n - k - 1) ],  g(v)=sigmoid(2.5 v),
//       u = x*256.  Terms negligible outside |u - k - 0.5| <= 4.5 -> 145 fine taps
//       at 1/16 resolution.
// Deposit: nearest fine node (midpoint rule), 1 INTEGER LDS atomic per sample
//          (ds_add_u32 — counts are exact; probing whether int LDS atomics are
//          bank-parallel vs the ~195 cyc/wave lane-serial rate measured for f32).
// Conv:   256 threads x 145 taps, int->float convert at read.

constexpr int KBINS   = 256;
constexpr int FSUB    = 16;                  // fine nodes per bin
constexpr int LPAD    = 64;                  // left halo (k=0 window reaches f=-64)
constexpr int TAPS    = 145;                 // window f in [16k-64, 16k+80]
// bank-skew addressing: addr = p + (p>>5); max logical p = 4224 -> 4356
constexpr int LDS_FH  = 4360;
constexpr int NPB     = 512 * 512;           // samples per batch
constexpr int BLK_PER_BATCH = 32;            // 8192 samples per block, grid = 256
constexpr int CHUNK   = NPB / BLK_PER_BATCH; // 8192

__device__ __forceinline__ int skew(int p) { return p + (p >> 5); }

__global__ __launch_bounds__(256)
void hist_kernel(const float* __restrict__ x, float* __restrict__ out) {
    __shared__ unsigned fh[LDS_FH];
    __shared__ float w[TAPS];
    const int tid = threadIdx.x;

    // zero fine hist
    #pragma unroll
    for (int i = tid; i < LDS_FH; i += 256) fh[i] = 0u;

    // conv weights: w[j] = sigmoid(0.15625*(j-64)) - sigmoid(0.15625*(j-80))
    if (tid < TAPS) {
        float a = 0.15625f * (float)(tid - 64);
        float b = 0.15625f * (float)(tid - 80);
        w[tid] = 1.f / (1.f + __expf(-a)) - 1.f / (1.f + __expf(-b));
    }
    __syncthreads();

    const int b     = blockIdx.x / BLK_PER_BATCH;
    const int chunk = blockIdx.x % BLK_PER_BATCH;
    const float4* xv = (const float4*)(x + (size_t)b * NPB + (size_t)chunk * CHUNK);

    // deposit: 8192 samples/block, 8 float4 per thread, 1 int LDS atomic per sample
    #pragma unroll
    for (int it = 0; it < CHUNK / (4 * 256); ++it) {
        float4 v = xv[it * 256 + tid];
        float vals[4] = {v.x, v.y, v.z, v.w};
        int addr[4];
        #pragma unroll
        for (int c = 0; c < 4; ++c) {
            float s = vals[c] * (float)(KBINS * FSUB);   // position on fine grid
            s = fminf(fmaxf(s, 0.f), 4096.f);            // defensive clamp
            addr[c] = skew((int)(s + 0.5f) + LPAD);      // nearest node (s >= 0)
        }
        #pragma unroll
        for (int c = 0; c < 4; ++c)
            atomicAdd(&fh[addr[c]], 1u);
    }
    __syncthreads();

    // convolve: thread k computes coarse bin k from taps [16k, 16k+144] (padded idx)
    {
        float acc = 0.f;
        const int base = tid * FSUB;
        #pragma unroll 8
        for (int j = 0; j < TAPS; ++j)
            acc += w[j] * (float)fh[skew(base + j)];
        unsafeAtomicAdd(&out[b * KBINS + tid], acc * (1.f / (float)NPB));
    }
}

extern "C" void kernel_launch(void* const* d_in, const int* in_sizes, int n_in,
                              void* d_out, int out_size, void* d_ws, size_t ws_size,
                              hipStream_t stream) {
    const float* x = (const float*)d_in[0];
    float* out = (float*)d_out;
    const int B = in_sizes[0] / NPB;   // 8

    hipMemsetAsync(d_out, 0, (size_t)out_size * sizeof(float), stream);
    hist_kernel<<<B * BLK_PER_BATCH, 256, 0, stream>>>(x, out);
}